// Round 10
// baseline (4053.913 us; speedup 1.0000x reference)
//
#include <hip/hip_runtime.h>
#include <hip/hip_bf16.h>
#include <math.h>

// Problem constants (DiscreteTransformer)
#define B_  8192
#define S_  16
#define E_  256
#define H_  8
#define FF_ 1024
#define L_  6
#define V_  512
#define U_  1024
#define DC_ 64
#define M_  (B_ * S_)     // 131072 tokens

typedef __attribute__((ext_vector_type(8))) short short8;   // 8 bf16 (4 VGPRs)
typedef __attribute__((ext_vector_type(4))) float f32x4;

// ---------------------------------------------------------------------------
// Wave (64-lane) reductions
// ---------------------------------------------------------------------------
__device__ __forceinline__ float wave_sum(float v) {
#pragma unroll
  for (int off = 32; off >= 1; off >>= 1) v += __shfl_xor(v, off);
  return v;
}
__device__ __forceinline__ float wave_max(float v) {
#pragma unroll
  for (int off = 32; off >= 1; off >>= 1) v = fmaxf(v, __shfl_xor(v, off));
  return v;
}

// bf16 <-> fp32 helpers (bf16 stored as short; RNE rounding on the way down)
__device__ __forceinline__ unsigned bfround(float f) {
  unsigned u = __builtin_bit_cast(unsigned, f);
  return (u + 0x7FFFu + ((u >> 16) & 1u)) >> 16;
}
__device__ __forceinline__ unsigned pack2(float lo, float hi) {
  return bfround(lo) | (bfround(hi) << 16);
}
__device__ __forceinline__ float b2f(short s) {
  return __builtin_bit_cast(float, (unsigned)(unsigned short)s << 16);
}
__device__ __forceinline__ float blo(unsigned u) { return __builtin_bit_cast(float, u << 16); }
__device__ __forceinline__ float bhi(unsigned u) { return __builtin_bit_cast(float, u & 0xFFFF0000u); }

// Async global -> LDS, 16 B per lane (global src per-lane, LDS dest linear).
__device__ __forceinline__ void gload_lds16(const void* g, void* l) {
  __builtin_amdgcn_global_load_lds(
      (const __attribute__((address_space(1))) void*)g,
      (__attribute__((address_space(3))) void*)l, 16, 0, 0);
}

// Bijective XCD-aware block swizzle (requires nblk % 8 == 0; all our grids are).
__device__ __forceinline__ int xcd_swz(int bid, int nblk) {
  return (bid & 7) * (nblk >> 3) + (bid >> 3);
}

// ---------------------------------------------------------------------------
// fp32 -> bf16 bulk conversion (exact grid; n % 1024 == 0)
// ---------------------------------------------------------------------------
__global__ void w2bf_kernel(const float* __restrict__ src, short* __restrict__ dst) {
  const int i = blockIdx.x * 256 + threadIdx.x;  // over n/4
  const float4 v = ((const float4*)src)[i];
  uint2 p;
  p.x = pack2(v.x, v.y);
  p.y = pack2(v.z, v.w);
  ((uint2*)dst)[i] = p;
}

// ---------------------------------------------------------------------------
// bf16-MFMA GEMM: C[M,N] = act(A[M,K] @ W[N,K]^T + bias[N] (+ res[M,N]))
// Tile 128x128xBK64; 256 threads = 4 waves (2x2); 4x4 16x16 frags/wave.
// global_load_lds width 16 + both-sides XOR swizzle (measured 0 conflicts).
// ---------------------------------------------------------------------------
template <int ACT, bool RES, bool OUTF32>
__launch_bounds__(256, 2)
__global__ void gemm_bf16_kernel(const short* __restrict__ A, const short* __restrict__ W,
                                 const float* __restrict__ bias, const short* __restrict__ res,
                                 void* __restrict__ Cv, int M, int N, int K) {
  __shared__ __align__(16) short As[128 * 64];
  __shared__ __align__(16) short Ws[128 * 64];
  const int t  = threadIdx.x;
  const int w  = t >> 6;
  const int l  = t & 63;
  const int wr = w >> 1;
  const int wc = w & 1;
  const int lr = l & 15;
  const int kg = l >> 4;
  const int nbn = N / 128;
  const int bid = xcd_swz(blockIdx.x, gridDim.x);
  const int bm = bid / nbn;
  const int bn = bid % nbn;
  const int m0 = bm * 128, n0 = bn * 128;

  f32x4 acc[4][4] = {};

  const int rg = l >> 3;
  const int cs = ((l & 7) ^ rg) * 8;
  const int swz = (lr & 7) * 8;

  for (int k0 = 0; k0 < K; k0 += 64) {
    const short* Ab = &A[(size_t)m0 * K + k0 + cs];
    const short* Wb = &W[(size_t)n0 * K + k0 + cs];
#pragma unroll
    for (int q = 0; q < 4; ++q) {
      const int i = w * 4 + q;
      const int row = i * 8 + rg;
      gload_lds16(Ab + (size_t)row * K, &As[i * 512]);
      gload_lds16(Wb + (size_t)row * K, &Ws[i * 512]);
    }
    __syncthreads();

#pragma unroll
    for (int kk = 0; kk < 64; kk += 32) {
      short8 af[4], bf[4];
#pragma unroll
      for (int mi = 0; mi < 4; ++mi)
        af[mi] = *(const short8*)&As[(wr * 64 + mi * 16 + lr) * 64 + ((kk + kg * 8) ^ swz)];
#pragma unroll
      for (int ni = 0; ni < 4; ++ni)
        bf[ni] = *(const short8*)&Ws[(wc * 64 + ni * 16 + lr) * 64 + ((kk + kg * 8) ^ swz)];
#pragma unroll
      for (int mi = 0; mi < 4; ++mi)
#pragma unroll
        for (int ni = 0; ni < 4; ++ni)
          acc[mi][ni] = __builtin_amdgcn_mfma_f32_16x16x32_bf16(af[mi], bf[ni], acc[mi][ni], 0, 0, 0);
    }
    __syncthreads();
  }

  float* Cf = (float*)Cv;
  short* Cb = (short*)Cv;
#pragma unroll
  for (int ni = 0; ni < 4; ++ni) {
    const int n = n0 + wc * 64 + ni * 16 + lr;
    const float bv = bias[n];
#pragma unroll
    for (int mi = 0; mi < 4; ++mi) {
      const int mbase = m0 + wr * 64 + mi * 16 + kg * 4;
#pragma unroll
      for (int j = 0; j < 4; ++j) {
        float z = acc[mi][ni][j] + bv;
        const size_t off = (size_t)(mbase + j) * N + n;
        if (RES) z += b2f(res[off]);
        if (ACT == 1) z = 0.5f * z * (1.0f + erff(z * 0.70710678118654752f));
        if (ACT == 2) z = fmaxf(z, 0.0f);
        if (OUTF32) Cf[off] = z;
        else        Cb[off] = (short)bfround(z);
      }
    }
  }
}

// ---------------------------------------------------------------------------
// Fused GEMM + residual + LayerNorm, N=256 (used for FF2+LN2, K=1024):
// Tile 64x256, 4 waves (2x2), per-wave 32x128 (2x8 frags). See R6 notes.
// ---------------------------------------------------------------------------
__launch_bounds__(256, 2)
__global__ void gemm_ln_kernel(const short* __restrict__ A, const short* __restrict__ W,
                               const float* __restrict__ bias, const short* __restrict__ res,
                               const float* __restrict__ g, const float* __restrict__ bb,
                               short* __restrict__ out, int M, int K) {
  __shared__ __align__(16) short As[64 * 64];
  __shared__ __align__(16) short Ws[256 * 64];
  __shared__ float lnbuf[64][2][2];
  const int t  = threadIdx.x;
  const int w  = t >> 6;
  const int l  = t & 63;
  const int wr = w >> 1;
  const int wc = w & 1;
  const int lr = l & 15;
  const int kg = l >> 4;
  const int bid = xcd_swz(blockIdx.x, gridDim.x);
  const int m0 = bid * 64;

  f32x4 acc[2][8] = {};

  const int rg = l >> 3;
  const int cs = ((l & 7) ^ rg) * 8;
  const int swz = (lr & 7) * 8;

  for (int k0 = 0; k0 < K; k0 += 64) {
    const short* Ab = &A[(size_t)m0 * K + k0 + cs];
    const short* Wb = &W[(size_t)0 * K + k0 + cs];
#pragma unroll
    for (int q = 0; q < 2; ++q) {
      const int i = w * 2 + q;
      gload_lds16(Ab + (size_t)(i * 8 + rg) * K, &As[i * 512]);
    }
#pragma unroll
    for (int q = 0; q < 8; ++q) {
      const int i = w * 8 + q;
      gload_lds16(Wb + (size_t)(i * 8 + rg) * K, &Ws[i * 512]);
    }
    __syncthreads();

#pragma unroll
    for (int kk = 0; kk < 64; kk += 32) {
      short8 af[2], bf[8];
#pragma unroll
      for (int mi = 0; mi < 2; ++mi)
        af[mi] = *(const short8*)&As[(wr * 32 + mi * 16 + lr) * 64 + ((kk + kg * 8) ^ swz)];
#pragma unroll
      for (int ni = 0; ni < 8; ++ni)
        bf[ni] = *(const short8*)&Ws[(wc * 128 + ni * 16 + lr) * 64 + ((kk + kg * 8) ^ swz)];
#pragma unroll
      for (int mi = 0; mi < 2; ++mi)
#pragma unroll
        for (int ni = 0; ni < 8; ++ni)
          acc[mi][ni] = __builtin_amdgcn_mfma_f32_16x16x32_bf16(af[mi], bf[ni], acc[mi][ni], 0, 0, 0);
    }
    __syncthreads();
  }

  float biasv[8], gv[8], bv[8];
#pragma unroll
  for (int ni = 0; ni < 8; ++ni) {
    const int n = wc * 128 + ni * 16 + lr;
    biasv[ni] = bias[n]; gv[ni] = g[n]; bv[ni] = bb[n];
  }
  float ps1[2][4] = {}, ps2[2][4] = {};
#pragma unroll
  for (int mi = 0; mi < 2; ++mi)
#pragma unroll
    for (int j = 0; j < 4; ++j) {
      const int m = m0 + wr * 32 + mi * 16 + kg * 4 + j;
#pragma unroll
      for (int ni = 0; ni < 8; ++ni) {
        const int n = wc * 128 + ni * 16 + lr;
        float z = acc[mi][ni][j] + biasv[ni] + b2f(res[(size_t)m * 256 + n]);
        acc[mi][ni][j] = z;
        ps1[mi][j] += z;
        ps2[mi][j] = fmaf(z, z, ps2[mi][j]);
      }
    }
#pragma unroll
  for (int off = 1; off <= 8; off <<= 1) {
#pragma unroll
    for (int mi = 0; mi < 2; ++mi)
#pragma unroll
      for (int j = 0; j < 4; ++j) {
        ps1[mi][j] += __shfl_xor(ps1[mi][j], off);
        ps2[mi][j] += __shfl_xor(ps2[mi][j], off);
      }
  }
  if (lr == 0) {
#pragma unroll
    for (int mi = 0; mi < 2; ++mi)
#pragma unroll
      for (int j = 0; j < 4; ++j) {
        const int r = wr * 32 + mi * 16 + kg * 4 + j;
        lnbuf[r][wc][0] = ps1[mi][j];
        lnbuf[r][wc][1] = ps2[mi][j];
      }
  }
  __syncthreads();

#pragma unroll
  for (int mi = 0; mi < 2; ++mi)
#pragma unroll
    for (int j = 0; j < 4; ++j) {
      const int r = wr * 32 + mi * 16 + kg * 4 + j;
      const float s1 = lnbuf[r][0][0] + lnbuf[r][1][0];
      const float s2 = lnbuf[r][0][1] + lnbuf[r][1][1];
      const float mu  = s1 * (1.0f / 256.0f);
      const float var = s2 * (1.0f / 256.0f) - mu * mu;
      const float rs  = 1.0f / sqrtf(var + 1e-5f);
      const size_t mrow = (size_t)(m0 + r) * 256;
#pragma unroll
      for (int ni = 0; ni < 8; ++ni) {
        const int n = wc * 128 + ni * 16 + lr;
        out[mrow + n] = (short)bfround((acc[mi][ni][j] - mu) * rs * gv[ni] + bv[ni]);
      }
    }
}

// ---------------------------------------------------------------------------
// Fused ATTENTION + Wo-GEMM + residual + LayerNorm (N=256, K=256):
// Block = 64 token rows (= 4 batch rows), 256 threads = 4 waves.
// Phase 1 (attention): wave w owns batch row w; 8 heads serially.
//   Scratch is WAVE-PRIVATE (floats [w*2048,(w+1)*2048) overlaying Ws), so
//   NO block barriers inside the head loop: CDNA wave64 is lockstep and the
//   compiler inserts lgkmcnt waits for intra-wave LDS RAW/WAR hazards.
//   wave_barrier() = zero-cost scheduling fence between sub-phases.
//   ONE __syncthreads() separates phase 1 from phase 2 (cross-wave oS reads
//   + Ws restaging). Note: wave w's phase-2 Ws staging region == its own
//   scratch (8 chunks x 512 shorts = 2048 floats), so no cross-wave WAR.
// Phase 2 (GEMM): A from swizzled oS (quad = col/8 ^ row&7 -> conflict-free
//   b128), W staged as in gemm_ln; epilogue = bias + residual + LN.
// ---------------------------------------------------------------------------
__launch_bounds__(256, 2)
__global__ void attn_wo_ln_kernel(const short* __restrict__ qkv, const short* __restrict__ W,
                                  const float* __restrict__ bias, const short* __restrict__ res,
                                  const float* __restrict__ g, const float* __restrict__ bb,
                                  short* __restrict__ out, int M) {
  __shared__ __align__(16) short oS[64 * 256];   // 32 KB swizzled o
  __shared__ __align__(16) short Ws[256 * 64];   // 32 KB (attn scratch overlay)
  __shared__ float lnbuf[64][2][2];
  const int t  = threadIdx.x;
  const int w  = t >> 6;
  const int l  = t & 63;
  const int wr = w >> 1;
  const int wc = w & 1;
  const int lr = l & 15;
  const int kg = l >> 4;
  const int bid = xcd_swz(blockIdx.x, gridDim.x);
  const int m0 = bid * 64;

  // ---- Phase 1: attention for batch row (m0/16 + w), 8 heads serially ----
  {
    float* scr = (float*)Ws;          // 8192 floats total, 2048 per wave
    float* sq = scr + w * 2048;       // [16][36]
    float* sk = sq + 576;             // [16][36]
    float* sv = sq + 1152;            // [16][36]
    float* sa = sq + 1728;            // [16][17]
    const int s  = l >> 2;
    const int d0 = (l & 3) * 8;
    const int sr = l & 15;
    const int tq = l >> 4;

    for (int hh = 0; hh < 8; ++hh) {
      {  // load q,k,v (16 rows x 32 d) -> wave-private scratch as fp32
        const size_t base = (size_t)(m0 + w * 16 + s) * 768 + hh * 32 + d0;
        const uint4 qv = *(const uint4*)&qkv[base];
        const uint4 kv = *(const uint4*)&qkv[base + 256];
        const uint4 vv = *(const uint4*)&qkv[base + 512];
        float* dq = &sq[s * 36 + d0];
        float* dk = &sk[s * 36 + d0];
        float* dv = &sv[s * 36 + d0];
        dq[0] = blo(qv.x); dq[1] = bhi(qv.x); dq[2] = blo(qv.y); dq[3] = bhi(qv.y);
        dq[4] = blo(qv.z); dq[5] = bhi(qv.z); dq[6] = blo(qv.w); dq[7] = bhi(qv.w);
        dk[0] = blo(kv.x); dk[1] = bhi(kv.x); dk[2] = blo(kv.y); dk[3] = bhi(kv.y);
        dk[4] = blo(kv.z); dk[5] = bhi(kv.z); dk[6] = blo(kv.w); dk[7] = bhi(kv.w);
        dv[0] = blo(vv.x); dv[1] = bhi(vv.x); dv[2] = blo(vv.y); dv[3] = bhi(vv.y);
        dv[4] = blo(vv.z); dv[5] = bhi(vv.z); dv[6] = blo(vv.w); dv[7] = bhi(vv.w);
      }
      __builtin_amdgcn_wave_barrier();   // intra-wave sched fence (0 cost)
      {  // scores + causal softmax: lane owns row sr, cols tq*4+j
        float sc[4] = {0.f, 0.f, 0.f, 0.f};
        for (int d = 0; d < 32; d += 4) {
          const float4 qv = *(const float4*)&sq[sr * 36 + d];
#pragma unroll
          for (int j = 0; j < 4; ++j) {
            const float4 kv = *(const float4*)&sk[(tq * 4 + j) * 36 + d];
            sc[j] += qv.x * kv.x + qv.y * kv.y + qv.z * kv.z + qv.w * kv.w;
          }
        }
        float mx = -1e30f;
#pragma unroll
        for (int j = 0; j < 4; ++j) {
          const int tt = tq * 4 + j;
          sc[j] = (tt > sr) ? -1e30f : sc[j] * 0.17677669529663687f;  // 1/sqrt(32)
          mx = fmaxf(mx, sc[j]);
        }
        mx = fmaxf(mx, __shfl_xor(mx, 16));
        mx = fmaxf(mx, __shfl_xor(mx, 32));
        float e[4]; float sm = 0.f;
#pragma unroll
        for (int j = 0; j < 4; ++j) { e[j] = expf(sc[j] - mx); sm += e[j]; }
        sm += __shfl_xor(sm, 16);
        sm += __shfl_xor(sm, 32);
#pragma unroll
        for (int j = 0; j < 4; ++j) sa[sr * 17 + tq * 4 + j] = e[j] / sm;
      }
      __builtin_amdgcn_wave_barrier();
      {  // o[s,d] = sum_t a[s,t] v[t,d]; write 8 bf16 to swizzled oS
        float a0[4] = {0.f, 0.f, 0.f, 0.f}, a1[4] = {0.f, 0.f, 0.f, 0.f};
        for (int tt = 0; tt < 16; ++tt) {
          const float av = sa[s * 17 + tt];
          const float4 v0 = *(const float4*)&sv[tt * 36 + d0];
          const float4 v1 = *(const float4*)&sv[tt * 36 + d0 + 4];
          a0[0] = fmaf(av, v0.x, a0[0]); a0[1] = fmaf(av, v0.y, a0[1]);
          a0[2] = fmaf(av, v0.z, a0[2]); a0[3] = fmaf(av, v0.w, a0[3]);
          a1[0] = fmaf(av, v1.x, a1[0]); a1[1] = fmaf(av, v1.y, a1[1]);
          a1[2] = fmaf(av, v1.z, a1[2]); a1[3] = fmaf(av, v1.w, a1[3]);
        }
        const int r = w * 16 + s;
        const int cphys = (hh * 32 + d0) ^ ((r & 7) * 8);
        uint4 p;
        p.x = pack2(a0[0], a0[1]); p.y = pack2(a0[2], a0[3]);
        p.z = pack2(a1[0], a1[1]); p.w = pack2(a1[2], a1[3]);
        *(uint4*)&oS[r * 256 + cphys] = p;
      }
      __builtin_amdgcn_wave_barrier();   // next head overwrites scratch (WAR)
    }
  }
  __syncthreads();  // oS complete across waves; Ws free for staging

  // ---- Phase 2: GEMM o@W^T (+bias+res) + LN.  A from oS, W staged. ----
  f32x4 acc[2][8] = {};
  const int rg = l >> 3;
  const int cs = ((l & 7) ^ rg) * 8;
  const int swz = (lr & 7) * 8;
  const int ar0 = wr * 32 + lr;            // A rows: +mi*16

  for (int k0 = 0; k0 < 256; k0 += 64) {
    const short* Wb = &W[(size_t)0 * 256 + k0 + cs];
#pragma unroll
    for (int q = 0; q < 8; ++q) {
      const int i = w * 8 + q;
      gload_lds16(Wb + (size_t)(i * 8 + rg) * 256, &Ws[i * 512]);
    }
    __syncthreads();

#pragma unroll
    for (int kk = 0; kk < 64; kk += 32) {
      short8 af[2], bf[8];
#pragma unroll
      for (int mi = 0; mi < 2; ++mi) {
        const int row = ar0 + mi * 16;
        const int col = k0 + kk + kg * 8;
        af[mi] = *(const short8*)&oS[row * 256 + (col ^ ((row & 7) * 8))];
      }
#pragma unroll
      for (int ni = 0; ni < 8; ++ni)
        bf[ni] = *(const short8*)&Ws[(wc * 128 + ni * 16 + lr) * 64 + ((kk + kg * 8) ^ swz)];
#pragma unroll
      for (int mi = 0; mi < 2; ++mi)
#pragma unroll
        for (int ni = 0; ni < 8; ++ni)
          acc[mi][ni] = __builtin_amdgcn_mfma_f32_16x16x32_bf16(af[mi], bf[ni], acc[mi][ni], 0, 0, 0);
    }
    __syncthreads();
  }

  float biasv[8], gv[8], bv[8];
#pragma unroll
  for (int ni = 0; ni < 8; ++ni) {
    const int n = wc * 128 + ni * 16 + lr;
    biasv[ni] = bias[n]; gv[ni] = g[n]; bv[ni] = bb[n];
  }
  float ps1[2][4] = {}, ps2[2][4] = {};
#pragma unroll
  for (int mi = 0; mi < 2; ++mi)
#pragma unroll
    for (int j = 0; j < 4; ++j) {
      const int m = m0 + wr * 32 + mi * 16 + kg * 4 + j;
#pragma unroll
      for (int ni = 0; ni < 8; ++ni) {
        const int n = wc * 128 + ni * 16 + lr;
        float z = acc[mi][ni][j] + biasv[ni] + b2f(res[(size_t)m * 256 + n]);
        acc[mi][ni][j] = z;
        ps1[mi][j] += z;
        ps2[mi][j] = fmaf(z, z, ps2[mi][j]);
      }
    }
#pragma unroll
  for (int off = 1; off <= 8; off <<= 1) {
#pragma unroll
    for (int mi = 0; mi < 2; ++mi)
#pragma unroll
      for (int j = 0; j < 4; ++j) {
        ps1[mi][j] += __shfl_xor(ps1[mi][j], off);
        ps2[mi][j] += __shfl_xor(ps2[mi][j], off);
      }
  }
  if (lr == 0) {
#pragma unroll
    for (int mi = 0; mi < 2; ++mi)
#pragma unroll
      for (int j = 0; j < 4; ++j) {
        const int r = wr * 32 + mi * 16 + kg * 4 + j;
        lnbuf[r][wc][0] = ps1[mi][j];
        lnbuf[r][wc][1] = ps2[mi][j];
      }
  }
  __syncthreads();

#pragma unroll
  for (int mi = 0; mi < 2; ++mi)
#pragma unroll
    for (int j = 0; j < 4; ++j) {
      const int r = wr * 32 + mi * 16 + kg * 4 + j;
      const float s1 = lnbuf[r][0][0] + lnbuf[r][1][0];
      const float s2 = lnbuf[r][0][1] + lnbuf[r][1][1];
      const float mu  = s1 * (1.0f / 256.0f);
      const float var = s2 * (1.0f / 256.0f) - mu * mu;
      const float rs  = 1.0f / sqrtf(var + 1e-5f);
      const size_t mrow = (size_t)(m0 + r) * 256;
#pragma unroll
      for (int ni = 0; ni < 8; ++ni) {
        const int n = wc * 128 + ni * 16 + lr;
        out[mrow + n] = (short)bfround((acc[mi][ni][j] - mu) * rs * gv[ni] + bv[ni]);
      }
    }
}

// ---------------------------------------------------------------------------
// Embedding (chunk-local bf16 h)
// ---------------------------------------------------------------------------
__global__ void embed_kernel(const int* __restrict__ x, const float* __restrict__ x_emb,
                             const float* __restrict__ pos_emb, const float* __restrict__ cproj,
                             short* __restrict__ h, int b0) {
  const int idx = blockIdx.x * 256 + threadIdx.x;
  const int e4 = idx & 63;
  const int s  = (idx >> 6) & 15;
  const int b  = b0 + (idx >> 10);
  const float4 pe = ((const float4*)pos_emb)[s * 64 + e4];
  const float4 cp = ((const float4*)cproj)[b * 64 + e4];
  float4 v;
  v.x = pe.x + cp.x; v.y = pe.y + cp.y; v.z = pe.z + cp.z; v.w = pe.w + cp.w;
  if (s > 0) {
    const int tok = x[b * 16 + s - 1];
    const float4 xe = ((const float4*)x_emb)[tok * 64 + e4];
    v.x += xe.x; v.y += xe.y; v.z += xe.z; v.w += xe.w;
  }
  uint2 p;
  p.x = pack2(v.x, v.y);
  p.y = pack2(v.z, v.w);
  ((uint2*)h)[idx] = p;
}

// ---------------------------------------------------------------------------
// Final: out[b] = sum_s ( logits[s_local, x[b,s]] - logsumexp_v )
// ---------------------------------------------------------------------------
__launch_bounds__(256)
__global__ void logprob_kernel(const float* __restrict__ logits, const int* __restrict__ x,
                               float* __restrict__ out, int b0) {
  const int w  = threadIdx.x >> 6;
  const int l  = threadIdx.x & 63;
  const int bl = blockIdx.x * 4 + w;
  const int b  = b0 + bl;
  float acc = 0.f;
  for (int s = 0; s < 16; ++s) {
    const float* row = logits + (size_t)(bl * 16 + s) * 512;
    float v[8];
#pragma unroll
    for (int i = 0; i < 8; ++i) v[i] = row[l + 64 * i];
    float mx = v[0];
#pragma unroll
    for (int i = 1; i < 8; ++i) mx = fmaxf(mx, v[i]);
    mx = wave_max(mx);
    float se = 0.f;
#pragma unroll
    for (int i = 0; i < 8; ++i) se += expf(v[i] - mx);
    se = wave_sum(se);
    const float lse = mx + logf(se);
    const float picked = row[x[b * 16 + s]];
    acc += picked - lse;
  }
  if (l == 0) out[b] = acc;
}

// ---------------------------------------------------------------------------
// Orchestration. Per layer: qkv->R, fused{attn+Wo+res+LN1}->h, FF1->R,
// fused{FF2+res+LN2}->h. Head: z0->R, z1->X, logits->R(fp32), logprob->out.
// ---------------------------------------------------------------------------
extern "C" void kernel_launch(void* const* d_in, const int* in_sizes, int n_in,
                              void* d_out, int out_size, void* d_ws, size_t ws_size,
                              hipStream_t stream) {
  const int*   x       = (const int*)  d_in[0];
  const float* c       = (const float*)d_in[1];
  const float* x_emb   = (const float*)d_in[2];
  const float* pos_emb = (const float*)d_in[3];
  const float* c_W     = (const float*)d_in[4];
  const float* c_b     = (const float*)d_in[5];
  const float* Wqkv    = (const float*)d_in[6];
  const float* bqkv    = (const float*)d_in[7];
  const float* Wo      = (const float*)d_in[8];
  const float* bo      = (const float*)d_in[9];
  const float* ln1_g   = (const float*)d_in[10];
  const float* ln1_b   = (const float*)d_in[11];
  const float* W1      = (const float*)d_in[12];
  const float* b1      = (const float*)d_in[13];
  const float* W2      = (const float*)d_in[14];
  const float* b2      = (const float*)d_in[15];
  const float* ln2_g   = (const float*)d_in[16];
  const float* ln2_b   = (const float*)d_in[17];
  const float* mW0     = (const float*)d_in[18];
  const float* mb0     = (const float*)d_in[19];
  const float* mW1     = (const float*)d_in[20];
  const float* mb1     = (const float*)d_in[21];
  const float* mW2     = (const float*)d_in[22];
  const float* mb2     = (const float*)d_in[23];
  float* out = (float*)d_out;

  // bf16 region element counts
  const size_t nWqkv = (size_t)L_ * 768 * 256;
  const size_t nWo   = (size_t)L_ * 256 * 256;
  const size_t nW1   = (size_t)L_ * 1024 * 256;
  const size_t nW2   = (size_t)L_ * 256 * 1024;
  const size_t nmW0  = (size_t)U_ * E_;
  const size_t nmW1  = (size_t)U_ * U_;
  const size_t nmW2  = (size_t)V_ * U_;
  const size_t ncW   = (size_t)E_ * DC_;
  const size_t nC    = (size_t)B_ * DC_;
  const size_t WBF   = nWqkv + nWo + nW1 + nW2 + nmW0 + nmW1 + nmW2 + ncW + nC;

  short* bWqkv = (short*)d_ws;
  short* bWo   = bWqkv + nWqkv;
  short* bW1   = bWo   + nWo;
  short* bW2   = bW1   + nW1;
  short* bmW0  = bW2   + nW2;
  short* bmW1  = bmW0  + nmW0;
  short* bmW2  = bmW1  + nmW1;
  short* bcW   = bmW2  + nmW2;
  short* bC    = bcW   + ncW;

  const size_t fixed_bytes = WBF * 2 + (size_t)B_ * 256 * 4;
  int BC = 0;
  for (int bc = B_; bc >= 128; bc >>= 1) {
    const size_t need = fixed_bytes + (size_t)bc * 16 * 2304 * 2;
    if (need <= ws_size) { BC = bc; break; }
  }
  if (BC == 0) return;
  const int MC = BC * 16;
  const int NCHUNK = B_ / BC;

  float* cpr = (float*)((char*)d_ws + WBF * 2);
  short* h   = (short*)(cpr + (size_t)B_ * 256);
  short* R   = h + (size_t)MC * 256;
  short* X   = R + (size_t)MC * 1024;
  float* logitsF = (float*)R;

  const dim3 blk(256);

  w2bf_kernel<<<dim3(nWqkv / 1024), blk, 0, stream>>>(Wqkv, bWqkv);
  w2bf_kernel<<<dim3(nWo   / 1024), blk, 0, stream>>>(Wo,   bWo);
  w2bf_kernel<<<dim3(nW1   / 1024), blk, 0, stream>>>(W1,   bW1);
  w2bf_kernel<<<dim3(nW2   / 1024), blk, 0, stream>>>(W2,   bW2);
  w2bf_kernel<<<dim3(nmW0  / 1024), blk, 0, stream>>>(mW0,  bmW0);
  w2bf_kernel<<<dim3(nmW1  / 1024), blk, 0, stream>>>(mW1,  bmW1);
  w2bf_kernel<<<dim3(nmW2  / 1024), blk, 0, stream>>>(mW2,  bmW2);
  w2bf_kernel<<<dim3(ncW   / 1024), blk, 0, stream>>>(c_W,  bcW);
  w2bf_kernel<<<dim3(nC    / 1024), blk, 0, stream>>>(c,    bC);

  gemm_bf16_kernel<0, false, true><<<dim3((B_ / 128) * (E_ / 128)), blk, 0, stream>>>(
      bC, bcW, c_b, nullptr, cpr, B_, E_, DC_);

  for (int ci = 0; ci < NCHUNK; ++ci) {
    const int b0 = ci * BC;
    embed_kernel<<<dim3((MC * 64) / 256), blk, 0, stream>>>(x, x_emb, pos_emb, cpr, h, b0);

    for (int l = 0; l < L_; ++l) {
      // qkv = h @ Wqkv^T + bqkv   [MC,768] bf16, K=256  -> R
      gemm_bf16_kernel<0, false, false><<<dim3((MC / 128) * (768 / 128)), blk, 0, stream>>>(
          h, bWqkv + (size_t)l * 768 * 256, bqkv + (size_t)l * 768, nullptr, R, MC, 768, 256);
      // h = LN1( attn(R) @ Wo^T + bo + h )   fused, in-place on h
      attn_wo_ln_kernel<<<dim3(MC / 64), blk, 0, stream>>>(
          R, bWo + (size_t)l * 256 * 256, bo + (size_t)l * 256, h,
          ln1_g + (size_t)l * 256, ln1_b + (size_t)l * 256, h, MC);
      // f = gelu(h @ W1^T + b1)   [MC,1024] bf16, K=256  -> R
      gemm_bf16_kernel<1, false, false><<<dim3((MC / 128) * (FF_ / 128)), blk, 0, stream>>>(
          h, bW1 + (size_t)l * 1024 * 256, b1 + (size_t)l * 1024, nullptr, R, MC, 1024, 256);
      // h = LN2( R @ W2^T + b2 + h )   fused, in-place on h, K=1024
      gemm_ln_kernel<<<dim3(MC / 64), blk, 0, stream>>>(
          R, bW2 + (size_t)l * 256 * 1024, b2 + (size_t)l * 256, h,
          ln2_g + (size_t)l * 256, ln2_b + (size_t)l * 256, h, MC, 1024);
    }

    // Head MLP (chunk-local)
    gemm_bf16_kernel<2, false, false><<<dim3((MC / 128) * (U_ / 128)), blk, 0, stream>>>(
        h, bmW0, mb0, nullptr, R, MC, U_, E_);
    gemm_bf16_kernel<2, false, false><<<dim3((MC / 128) * (U_ / 128)), blk, 0, stream>>>(
        R, bmW1, mb1, nullptr, X, MC, U_, U_);
    gemm_bf16_kernel<0, false, true><<<dim3((MC / 128) * (V_ / 128)), blk, 0, stream>>>(
        X, bmW2, mb2, nullptr, logitsF, MC, V_, U_);

    logprob_kernel<<<dim3(BC / 4), blk, 0, stream>>>(logitsF, x, out, b0);
  }
}

// Round 12
// 3639.531 us; speedup vs baseline: 1.1139x; 1.1139x over previous
//
#include <hip/hip_runtime.h>
#include <hip/hip_bf16.h>
#include <math.h>

// Problem constants (DiscreteTransformer)
#define B_  8192
#define S_  16
#define E_  256
#define H_  8
#define FF_ 1024
#define L_  6
#define V_  512
#define U_  1024
#define DC_ 64
#define M_  (B_ * S_)     // 131072 tokens

typedef __attribute__((ext_vector_type(8))) short short8;   // 8 bf16 (4 VGPRs)
typedef __attribute__((ext_vector_type(4))) float f32x4;

// ---------------------------------------------------------------------------
// Wave (64-lane) reductions
// ---------------------------------------------------------------------------
__device__ __forceinline__ float wave_sum(float v) {
#pragma unroll
  for (int off = 32; off >= 1; off >>= 1) v += __shfl_xor(v, off);
  return v;
}
__device__ __forceinline__ float wave_max(float v) {
#pragma unroll
  for (int off = 32; off >= 1; off >>= 1) v = fmaxf(v, __shfl_xor(v, off));
  return v;
}

// bf16 <-> fp32 helpers (bf16 stored as short; RNE rounding on the way down)
__device__ __forceinline__ unsigned bfround(float f) {
  unsigned u = __builtin_bit_cast(unsigned, f);
  return (u + 0x7FFFu + ((u >> 16) & 1u)) >> 16;
}
__device__ __forceinline__ unsigned pack2(float lo, float hi) {
  return bfround(lo) | (bfround(hi) << 16);
}
__device__ __forceinline__ float b2f(short s) {
  return __builtin_bit_cast(float, (unsigned)(unsigned short)s << 16);
}
__device__ __forceinline__ float blo(unsigned u) { return __builtin_bit_cast(float, u << 16); }
__device__ __forceinline__ float bhi(unsigned u) { return __builtin_bit_cast(float, u & 0xFFFF0000u); }

// Async global -> LDS, 16 B per lane (global src per-lane, LDS dest linear).
__device__ __forceinline__ void gload_lds16(const void* g, void* l) {
  __builtin_amdgcn_global_load_lds(
      (const __attribute__((address_space(1))) void*)g,
      (__attribute__((address_space(3))) void*)l, 16, 0, 0);
}

// Bijective XCD-aware block swizzle (requires nblk % 8 == 0; all our grids are).
__device__ __forceinline__ int xcd_swz(int bid, int nblk) {
  return (bid & 7) * (nblk >> 3) + (bid >> 3);
}

// ---------------------------------------------------------------------------
// fp32 -> bf16 bulk conversion (exact grid; n % 1024 == 0)
// ---------------------------------------------------------------------------
__global__ void w2bf_kernel(const float* __restrict__ src, short* __restrict__ dst) {
  const int i = blockIdx.x * 256 + threadIdx.x;  // over n/4
  const float4 v = ((const float4*)src)[i];
  uint2 p;
  p.x = pack2(v.x, v.y);
  p.y = pack2(v.z, v.w);
  ((uint2*)dst)[i] = p;
}

// ---------------------------------------------------------------------------
// bf16-MFMA GEMM: C[M,N] = act(A[M,K] @ W[N,K]^T + bias[N] (+ res[M,N]))
// Tile 128x128xBK64; 256 threads = 4 waves (2x2); 4x4 16x16 frags/wave.
// global_load_lds width 16 + both-sides XOR swizzle (measured 0 conflicts).
// ---------------------------------------------------------------------------
template <int ACT, bool RES, bool OUTF32>
__launch_bounds__(256, 2)
__global__ void gemm_bf16_kernel(const short* __restrict__ A, const short* __restrict__ W,
                                 const float* __restrict__ bias, const short* __restrict__ res,
                                 void* __restrict__ Cv, int M, int N, int K) {
  __shared__ __align__(16) short As[128 * 64];
  __shared__ __align__(16) short Ws[128 * 64];
  const int t  = threadIdx.x;
  const int w  = t >> 6;
  const int l  = t & 63;
  const int wr = w >> 1;
  const int wc = w & 1;
  const int lr = l & 15;
  const int kg = l >> 4;
  const int nbn = N / 128;
  const int bid = xcd_swz(blockIdx.x, gridDim.x);
  const int bm = bid / nbn;
  const int bn = bid % nbn;
  const int m0 = bm * 128, n0 = bn * 128;

  f32x4 acc[4][4] = {};

  const int rg = l >> 3;
  const int cs = ((l & 7) ^ rg) * 8;
  const int swz = (lr & 7) * 8;

  for (int k0 = 0; k0 < K; k0 += 64) {
    const short* Ab = &A[(size_t)m0 * K + k0 + cs];
    const short* Wb = &W[(size_t)n0 * K + k0 + cs];
#pragma unroll
    for (int q = 0; q < 4; ++q) {
      const int i = w * 4 + q;
      const int row = i * 8 + rg;
      gload_lds16(Ab + (size_t)row * K, &As[i * 512]);
      gload_lds16(Wb + (size_t)row * K, &Ws[i * 512]);
    }
    __syncthreads();

#pragma unroll
    for (int kk = 0; kk < 64; kk += 32) {
      short8 af[4], bf[4];
#pragma unroll
      for (int mi = 0; mi < 4; ++mi)
        af[mi] = *(const short8*)&As[(wr * 64 + mi * 16 + lr) * 64 + ((kk + kg * 8) ^ swz)];
#pragma unroll
      for (int ni = 0; ni < 4; ++ni)
        bf[ni] = *(const short8*)&Ws[(wc * 64 + ni * 16 + lr) * 64 + ((kk + kg * 8) ^ swz)];
#pragma unroll
      for (int mi = 0; mi < 4; ++mi)
#pragma unroll
        for (int ni = 0; ni < 4; ++ni)
          acc[mi][ni] = __builtin_amdgcn_mfma_f32_16x16x32_bf16(af[mi], bf[ni], acc[mi][ni], 0, 0, 0);
    }
    __syncthreads();
  }

  float* Cf = (float*)Cv;
  short* Cb = (short*)Cv;
#pragma unroll
  for (int ni = 0; ni < 4; ++ni) {
    const int n = n0 + wc * 64 + ni * 16 + lr;
    const float bv = bias[n];
#pragma unroll
    for (int mi = 0; mi < 4; ++mi) {
      const int mbase = m0 + wr * 64 + mi * 16 + kg * 4;
#pragma unroll
      for (int j = 0; j < 4; ++j) {
        float z = acc[mi][ni][j] + bv;
        const size_t off = (size_t)(mbase + j) * N + n;
        if (RES) z += b2f(res[off]);
        if (ACT == 1) z = 0.5f * z * (1.0f + erff(z * 0.70710678118654752f));
        if (ACT == 2) z = fmaxf(z, 0.0f);
        if (OUTF32) Cf[off] = z;
        else        Cb[off] = (short)bfround(z);
      }
    }
  }
}

// ---------------------------------------------------------------------------
// Fused GEMM + residual + LayerNorm, N=256 (Wo+LN1 K=256; FF2+LN2 K=1024):
// Tile 64x256, 4 waves (2x2), per-wave 32x128 (2x8 frags). In-place out==res
// safe (res reads precede the barrier preceding writes; blocks own disjoint
// rows). fp32 z through LN. (Verified R8: 3.84 ms.)
// ---------------------------------------------------------------------------
__launch_bounds__(256, 2)
__global__ void gemm_ln_kernel(const short* __restrict__ A, const short* __restrict__ W,
                               const float* __restrict__ bias, const short* __restrict__ res,
                               const float* __restrict__ g, const float* __restrict__ bb,
                               short* __restrict__ out, int M, int K) {
  __shared__ __align__(16) short As[64 * 64];
  __shared__ __align__(16) short Ws[256 * 64];
  __shared__ float lnbuf[64][2][2];
  const int t  = threadIdx.x;
  const int w  = t >> 6;
  const int l  = t & 63;
  const int wr = w >> 1;
  const int wc = w & 1;
  const int lr = l & 15;
  const int kg = l >> 4;
  const int bid = xcd_swz(blockIdx.x, gridDim.x);
  const int m0 = bid * 64;

  f32x4 acc[2][8] = {};

  const int rg = l >> 3;
  const int cs = ((l & 7) ^ rg) * 8;
  const int swz = (lr & 7) * 8;

  for (int k0 = 0; k0 < K; k0 += 64) {
    const short* Ab = &A[(size_t)m0 * K + k0 + cs];
    const short* Wb = &W[(size_t)0 * K + k0 + cs];
#pragma unroll
    for (int q = 0; q < 2; ++q) {
      const int i = w * 2 + q;
      gload_lds16(Ab + (size_t)(i * 8 + rg) * K, &As[i * 512]);
    }
#pragma unroll
    for (int q = 0; q < 8; ++q) {
      const int i = w * 8 + q;
      gload_lds16(Wb + (size_t)(i * 8 + rg) * K, &Ws[i * 512]);
    }
    __syncthreads();

#pragma unroll
    for (int kk = 0; kk < 64; kk += 32) {
      short8 af[2], bf[8];
#pragma unroll
      for (int mi = 0; mi < 2; ++mi)
        af[mi] = *(const short8*)&As[(wr * 32 + mi * 16 + lr) * 64 + ((kk + kg * 8) ^ swz)];
#pragma unroll
      for (int ni = 0; ni < 8; ++ni)
        bf[ni] = *(const short8*)&Ws[(wc * 128 + ni * 16 + lr) * 64 + ((kk + kg * 8) ^ swz)];
#pragma unroll
      for (int mi = 0; mi < 2; ++mi)
#pragma unroll
        for (int ni = 0; ni < 8; ++ni)
          acc[mi][ni] = __builtin_amdgcn_mfma_f32_16x16x32_bf16(af[mi], bf[ni], acc[mi][ni], 0, 0, 0);
    }
    __syncthreads();
  }

  float biasv[8], gv[8], bv[8];
#pragma unroll
  for (int ni = 0; ni < 8; ++ni) {
    const int n = wc * 128 + ni * 16 + lr;
    biasv[ni] = bias[n]; gv[ni] = g[n]; bv[ni] = bb[n];
  }
  float ps1[2][4] = {}, ps2[2][4] = {};
#pragma unroll
  for (int mi = 0; mi < 2; ++mi)
#pragma unroll
    for (int j = 0; j < 4; ++j) {
      const int m = m0 + wr * 32 + mi * 16 + kg * 4 + j;
#pragma unroll
      for (int ni = 0; ni < 8; ++ni) {
        const int n = wc * 128 + ni * 16 + lr;
        float z = acc[mi][ni][j] + biasv[ni] + b2f(res[(size_t)m * 256 + n]);
        acc[mi][ni][j] = z;
        ps1[mi][j] += z;
        ps2[mi][j] = fmaf(z, z, ps2[mi][j]);
      }
    }
#pragma unroll
  for (int off = 1; off <= 8; off <<= 1) {
#pragma unroll
    for (int mi = 0; mi < 2; ++mi)
#pragma unroll
      for (int j = 0; j < 4; ++j) {
        ps1[mi][j] += __shfl_xor(ps1[mi][j], off);
        ps2[mi][j] += __shfl_xor(ps2[mi][j], off);
      }
  }
  if (lr == 0) {
#pragma unroll
    for (int mi = 0; mi < 2; ++mi)
#pragma unroll
      for (int j = 0; j < 4; ++j) {
        const int r = wr * 32 + mi * 16 + kg * 4 + j;
        lnbuf[r][wc][0] = ps1[mi][j];
        lnbuf[r][wc][1] = ps2[mi][j];
      }
  }
  __syncthreads();

#pragma unroll
  for (int mi = 0; mi < 2; ++mi)
#pragma unroll
    for (int j = 0; j < 4; ++j) {
      const int r = wr * 32 + mi * 16 + kg * 4 + j;
      const float s1 = lnbuf[r][0][0] + lnbuf[r][1][0];
      const float s2 = lnbuf[r][0][1] + lnbuf[r][1][1];
      const float mu  = s1 * (1.0f / 256.0f);
      const float var = s2 * (1.0f / 256.0f) - mu * mu;
      const float rs  = 1.0f / sqrtf(var + 1e-5f);
      const size_t mrow = (size_t)(m0 + r) * 256;
#pragma unroll
      for (int ni = 0; ni < 8; ++ni) {
        const int n = wc * 128 + ni * 16 + lr;
        out[mrow + n] = (short)bfround((acc[mi][ni][j] - mu) * rs * gv[ni] + bv[ni]);
      }
    }
}

// ---------------------------------------------------------------------------
// Fused logits-GEMM + log-prob (replaces logits + logprob kernels):
//   z[64,512] = X[m0:m0+64] @ mW2^T + mb2   (K=1024, two N-halves of 256)
//   out[b]    = sum_{s} ( z[r][x[b,s]] - logsumexp_v z[r][v] )   r=bb*16+s
// Block covers 64 token rows = 4 COMPLETE batch rows -> LSE + picked + sum
// finish in-block; logits never touch HBM. Online logsumexp across halves.
// Staging/frag algebra identical to gemm_ln (both-sides swizzle).
// ---------------------------------------------------------------------------
__launch_bounds__(256, 2)
__global__ void gemm_lp_kernel(const short* __restrict__ A, const short* __restrict__ W,
                               const float* __restrict__ bias, const int* __restrict__ x,
                               float* __restrict__ out, int b0) {
  __shared__ __align__(16) short As[64 * 64];
  __shared__ __align__(16) short Ws[256 * 64];
  __shared__ float redm[64][2];   // per-row per-wc partial max
  __shared__ float reds[64][2];   // per-row per-wc partial sumexp
  __shared__ float run_m[64], run_s[64], pickb[64];
  __shared__ int   xb[64];
  const int t  = threadIdx.x;
  const int w  = t >> 6;
  const int l  = t & 63;
  const int wr = w >> 1;
  const int wc = w & 1;
  const int lr = l & 15;
  const int kg = l >> 4;
  const int bid = xcd_swz(blockIdx.x, gridDim.x);
  const int m0 = bid * 64;

  if (t < 64) {
    xb[t]   = x[(size_t)b0 * 16 + m0 + t];  // x flat [B,16]: global token index
    run_m[t] = -1e30f;
    run_s[t] = 0.f;
  }
  __syncthreads();

  const int rg = l >> 3;
  const int cs = ((l & 7) ^ rg) * 8;
  const int swz = (lr & 7) * 8;

  for (int half = 0; half < 2; ++half) {
    f32x4 acc[2][8] = {};
    for (int k0 = 0; k0 < 1024; k0 += 64) {
      const short* Ab = &A[(size_t)m0 * 1024 + k0 + cs];
      const short* Wb = &W[(size_t)(half * 256) * 1024 + k0 + cs];
#pragma unroll
      for (int q = 0; q < 2; ++q) {
        const int i = w * 2 + q;
        gload_lds16(Ab + (size_t)(i * 8 + rg) * 1024, &As[i * 512]);
      }
#pragma unroll
      for (int q = 0; q < 8; ++q) {
        const int i = w * 8 + q;
        gload_lds16(Wb + (size_t)(i * 8 + rg) * 1024, &Ws[i * 512]);
      }
      __syncthreads();
#pragma unroll
      for (int kk = 0; kk < 64; kk += 32) {
        short8 af[2], bf[8];
#pragma unroll
        for (int mi = 0; mi < 2; ++mi)
          af[mi] = *(const short8*)&As[(wr * 32 + mi * 16 + lr) * 64 + ((kk + kg * 8) ^ swz)];
#pragma unroll
        for (int ni = 0; ni < 8; ++ni)
          bf[ni] = *(const short8*)&Ws[(wc * 128 + ni * 16 + lr) * 64 + ((kk + kg * 8) ^ swz)];
#pragma unroll
        for (int mi = 0; mi < 2; ++mi)
#pragma unroll
          for (int ni = 0; ni < 8; ++ni)
            acc[mi][ni] = __builtin_amdgcn_mfma_f32_16x16x32_bf16(af[mi], bf[ni], acc[mi][ni], 0, 0, 0);
      }
      __syncthreads();
    }

    // z = acc + bias (kept in acc); per-row partial max -> redm
    float bv[8];
#pragma unroll
    for (int ni = 0; ni < 8; ++ni)
      bv[ni] = bias[half * 256 + wc * 128 + ni * 16 + lr];
#pragma unroll
    for (int mi = 0; mi < 2; ++mi)
#pragma unroll
      for (int j = 0; j < 4; ++j) {
        float pm = -1e30f;
#pragma unroll
        for (int ni = 0; ni < 8; ++ni) {
          const float z = acc[mi][ni][j] + bv[ni];
          acc[mi][ni][j] = z;
          pm = fmaxf(pm, z);
        }
#pragma unroll
        for (int off = 1; off <= 8; off <<= 1) pm = fmaxf(pm, __shfl_xor(pm, off));
        if (lr == 0) redm[wr * 32 + mi * 16 + kg * 4 + j][wc] = pm;
      }
    __syncthreads();

    // sumexp with the shared row max; grab picked logit if column matches
#pragma unroll
    for (int mi = 0; mi < 2; ++mi)
#pragma unroll
      for (int j = 0; j < 4; ++j) {
        const int r  = wr * 32 + mi * 16 + kg * 4 + j;
        const float rm = fmaxf(redm[r][0], redm[r][1]);
        const int  xv = xb[r];
        float ps = 0.f;
#pragma unroll
        for (int ni = 0; ni < 8; ++ni) {
          const float z = acc[mi][ni][j];
          ps += expf(z - rm);
          const int col = half * 256 + wc * 128 + ni * 16 + lr;
          if (col == xv) pickb[r] = z;
        }
#pragma unroll
        for (int off = 1; off <= 8; off <<= 1) ps += __shfl_xor(ps, off);
        if (lr == 0) reds[r][wc] = ps;
      }
    __syncthreads();

    // online combine (one thread per row: wc==0, lr==0)
    if (wc == 0 && lr == 0) {
#pragma unroll
      for (int mi = 0; mi < 2; ++mi)
#pragma unroll
        for (int j = 0; j < 4; ++j) {
          const int r = wr * 32 + mi * 16 + kg * 4 + j;
          const float m1 = fmaxf(redm[r][0], redm[r][1]);
          const float s1 = reds[r][0] + reds[r][1];
          const float mo = run_m[r];
          const float mn = fmaxf(mo, m1);
          run_s[r] = run_s[r] * expf(mo - mn) + s1 * expf(m1 - mn);
          run_m[r] = mn;
        }
    }
    __syncthreads();  // orders run_m/run_s (and next half's staging)
  }

  if (t < 4) {  // 4 complete batch rows per block
    float lp = 0.f;
#pragma unroll
    for (int s = 0; s < 16; ++s) {
      const int r = t * 16 + s;
      lp += pickb[r] - (run_m[r] + logf(run_s[r]));
    }
    out[b0 + (m0 >> 4) + t] = lp;
  }
}

// ---------------------------------------------------------------------------
// Embedding (chunk-local bf16 h)
// ---------------------------------------------------------------------------
__global__ void embed_kernel(const int* __restrict__ x, const float* __restrict__ x_emb,
                             const float* __restrict__ pos_emb, const float* __restrict__ cproj,
                             short* __restrict__ h, int b0) {
  const int idx = blockIdx.x * 256 + threadIdx.x;
  const int e4 = idx & 63;
  const int s  = (idx >> 6) & 15;
  const int b  = b0 + (idx >> 10);
  const float4 pe = ((const float4*)pos_emb)[s * 64 + e4];
  const float4 cp = ((const float4*)cproj)[b * 64 + e4];
  float4 v;
  v.x = pe.x + cp.x; v.y = pe.y + cp.y; v.z = pe.z + cp.z; v.w = pe.w + cp.w;
  if (s > 0) {
    const int tok = x[b * 16 + s - 1];
    const float4 xe = ((const float4*)x_emb)[tok * 64 + e4];
    v.x += xe.x; v.y += xe.y; v.z += xe.z; v.w += xe.w;
  }
  uint2 p;
  p.x = pack2(v.x, v.y);
  p.y = pack2(v.z, v.w);
  ((uint2*)h)[idx] = p;
}

// ---------------------------------------------------------------------------
// Attention (chunk-local, bf16 I/O): per (b_local, head) on one wave. S=16,
// dh=32. High-occupancy standalone version (R8-verified: best so far).
// ---------------------------------------------------------------------------
__launch_bounds__(256)
__global__ void attn_kernel(const short* __restrict__ qkv, short* __restrict__ o) {
  __shared__ __align__(16) float sq[4][16][36];
  __shared__ __align__(16) float sk[4][16][36];
  __shared__ __align__(16) float sv[4][16][36];
  __shared__ float sa[4][16][17];
  const int w   = threadIdx.x >> 6;
  const int l   = threadIdx.x & 63;
  const int gid = blockIdx.x * 4 + w;   // = b_local*8 + head
  const int b   = gid >> 3;
  const int hh  = gid & 7;

  {
    const int s  = l >> 2;
    const int d0 = (l & 3) * 8;
    const size_t base = (size_t)(b * 16 + s) * 768 + hh * 32 + d0;
    const uint4 qv = *(const uint4*)&qkv[base];
    const uint4 kv = *(const uint4*)&qkv[base + 256];
    const uint4 vv = *(const uint4*)&qkv[base + 512];
    float* dq = &sq[w][s][d0];
    float* dk = &sk[w][s][d0];
    float* dv = &sv[w][s][d0];
    dq[0] = blo(qv.x); dq[1] = bhi(qv.x); dq[2] = blo(qv.y); dq[3] = bhi(qv.y);
    dq[4] = blo(qv.z); dq[5] = bhi(qv.z); dq[6] = blo(qv.w); dq[7] = bhi(qv.w);
    dk[0] = blo(kv.x); dk[1] = bhi(kv.x); dk[2] = blo(kv.y); dk[3] = bhi(kv.y);
    dk[4] = blo(kv.z); dk[5] = bhi(kv.z); dk[6] = blo(kv.w); dk[7] = bhi(kv.w);
    dv[0] = blo(vv.x); dv[1] = bhi(vv.x); dv[2] = blo(vv.y); dv[3] = bhi(vv.y);
    dv[4] = blo(vv.z); dv[5] = bhi(vv.z); dv[6] = blo(vv.w); dv[7] = bhi(vv.w);
  }
  __syncthreads();

  {
    const int sr = l & 15;
    const int tq = l >> 4;
    float sc[4] = {0.f, 0.f, 0.f, 0.f};
    for (int d = 0; d < 32; d += 4) {
      const float4 qv = *(const float4*)&sq[w][sr][d];
#pragma unroll
      for (int j = 0; j < 4; ++j) {
        const float4 kv = *(const float4*)&sk[w][tq * 4 + j][d];
        sc[j] += qv.x * kv.x + qv.y * kv.y + qv.z * kv.z + qv.w * kv.w;
      }
    }
    float mx = -1e30f;
#pragma unroll
    for (int j = 0; j < 4; ++j) {
      const int tt = tq * 4 + j;
      sc[j] = (tt > sr) ? -1e30f : sc[j] * 0.17677669529663687f;  // 1/sqrt(32)
      mx = fmaxf(mx, sc[j]);
    }
    mx = fmaxf(mx, __shfl_xor(mx, 16));
    mx = fmaxf(mx, __shfl_xor(mx, 32));
    float e[4]; float sm = 0.f;
#pragma unroll
    for (int j = 0; j < 4; ++j) { e[j] = expf(sc[j] - mx); sm += e[j]; }
    sm += __shfl_xor(sm, 16);
    sm += __shfl_xor(sm, 32);
#pragma unroll
    for (int j = 0; j < 4; ++j) sa[w][sr][tq * 4 + j] = e[j] / sm;
  }
  __syncthreads();

  {
    const int s  = l >> 2;
    const int d0 = (l & 3) * 8;
    float a0[4] = {0.f, 0.f, 0.f, 0.f}, a1[4] = {0.f, 0.f, 0.f, 0.f};
    for (int tt = 0; tt < 16; ++tt) {
      const float av = sa[w][s][tt];
      const float4 v0 = *(const float4*)&sv[w][tt][d0];
      const float4 v1 = *(const float4*)&sv[w][tt][d0 + 4];
      a0[0] = fmaf(av, v0.x, a0[0]); a0[1] = fmaf(av, v0.y, a0[1]);
      a0[2] = fmaf(av, v0.z, a0[2]); a0[3] = fmaf(av, v0.w, a0[3]);
      a1[0] = fmaf(av, v1.x, a1[0]); a1[1] = fmaf(av, v1.y, a1[1]);
      a1[2] = fmaf(av, v1.z, a1[2]); a1[3] = fmaf(av, v1.w, a1[3]);
    }
    const size_t ob = (size_t)(b * 16 + s) * 256 + hh * 32 + d0;
    uint4 p;
    p.x = pack2(a0[0], a0[1]); p.y = pack2(a0[2], a0[3]);
    p.z = pack2(a1[0], a1[1]); p.w = pack2(a1[2], a1[3]);
    *(uint4*)&o[ob] = p;
  }
}

// ---------------------------------------------------------------------------
// Orchestration (R8 structure + fused logits/logprob). Per layer: qkv->R,
// attn->X, fused{Wo+res+LN1}->h, FF1->R, fused{FF2+res+LN2}->h.
// Head: z0->R, z1->X, fused{logits+logprob}(X)->out.
// ---------------------------------------------------------------------------
extern "C" void kernel_launch(void* const* d_in, const int* in_sizes, int n_in,
                              void* d_out, int out_size, void* d_ws, size_t ws_size,
                              hipStream_t stream) {
  const int*   x       = (const int*)  d_in[0];
  const float* c       = (const float*)d_in[1];
  const float* x_emb   = (const float*)d_in[2];
  const float* pos_emb = (const float*)d_in[3];
  const float* c_W     = (const float*)d_in[4];
  const float* c_b     = (const float*)d_in[5];
  const float* Wqkv    = (const float*)d_in[6];
  const float* bqkv    = (const float*)d_in[7];
  const float* Wo      = (const float*)d_in[8];
  const float* bo      = (const float*)d_in[9];
  const float* ln1_g   = (const float*)d_in[10];
  const float* ln1_b   = (const float*)d_in[11];
  const float* W1      = (const float*)d_in[12];
  const float* b1      = (const float*)d_in[13];
  const float* W2      = (const float*)d_in[14];
  const float* b2      = (const float*)d_in[15];
  const float* ln2_g   = (const float*)d_in[16];
  const float* ln2_b   = (const float*)d_in[17];
  const float* mW0     = (const float*)d_in[18];
  const float* mb0     = (const float*)d_in[19];
  const float* mW1     = (const float*)d_in[20];
  const float* mb1     = (const float*)d_in[21];
  const float* mW2     = (const float*)d_in[22];
  const float* mb2     = (const float*)d_in[23];
  float* out = (float*)d_out;

  // bf16 region element counts
  const size_t nWqkv = (size_t)L_ * 768 * 256;
  const size_t nWo   = (size_t)L_ * 256 * 256;
  const size_t nW1   = (size_t)L_ * 1024 * 256;
  const size_t nW2   = (size_t)L_ * 256 * 1024;
  const size_t nmW0  = (size_t)U_ * E_;
  const size_t nmW1  = (size_t)U_ * U_;
  const size_t nmW2  = (size_t)V_ * U_;
  const size_t ncW   = (size_t)E_ * DC_;
  const size_t nC    = (size_t)B_ * DC_;
  const size_t WBF   = nWqkv + nWo + nW1 + nW2 + nmW0 + nmW1 + nmW2 + ncW + nC;

  short* bWqkv = (short*)d_ws;
  short* bWo   = bWqkv + nWqkv;
  short* bW1   = bWo   + nWo;
  short* bW2   = bW1   + nW1;
  short* bmW0  = bW2   + nW2;
  short* bmW1  = bmW0  + nmW0;
  short* bmW2  = bmW1  + nmW1;
  short* bcW   = bmW2  + nmW2;
  short* bC    = bcW   + ncW;

  const size_t fixed_bytes = WBF * 2 + (size_t)B_ * 256 * 4;
  int BC = 0;
  for (int bc = B_; bc >= 128; bc >>= 1) {
    const size_t need = fixed_bytes + (size_t)bc * 16 * 2304 * 2;
    if (need <= ws_size) { BC = bc; break; }
  }
  if (BC == 0) return;
  const int MC = BC * 16;
  const int NCHUNK = B_ / BC;

  float* cpr = (float*)((char*)d_ws + WBF * 2);
  short* h   = (short*)(cpr + (size_t)B_ * 256);
  short* R   = h + (size_t)MC * 256;
  short* X   = R + (size_t)MC * 1024;

  const dim3 blk(256);

  w2bf_kernel<<<dim3(nWqkv / 1024), blk, 0, stream>>>(Wqkv, bWqkv);
  w2bf_kernel<<<dim3(nWo   / 1024), blk, 0, stream>>>(Wo,   bWo);
  w2bf_kernel<<<dim3(nW1   / 1024), blk, 0, stream>>>(W1,   bW1);
  w2bf_kernel<<<dim3(nW2   / 1024), blk, 0, stream>>>(W2,   bW2);
  w2bf_kernel<<<dim3(nmW0  / 1024), blk, 0, stream>>>(mW0,  bmW0);
  w2bf_kernel<<<dim3(nmW1  / 1024), blk, 0, stream>>>(mW1,  bmW1);
  w2bf_kernel<<<dim3(nmW2  / 1024), blk, 0, stream>>>(mW2,  bmW2);
  w2bf_kernel<<<dim3(ncW   / 1024), blk, 0, stream>>>(c_W,  bcW);
  w2bf_kernel<<<dim3(nC    / 1024), blk, 0, stream>>>(c,    bC);

  gemm_bf16_kernel<0, false, true><<<dim3((B_ / 128) * (E_ / 128)), blk, 0, stream>>>(
      bC, bcW, c_b, nullptr, cpr, B_, E_, DC_);

  for (int ci = 0; ci < NCHUNK; ++ci) {
    const int b0 = ci * BC;
    embed_kernel<<<dim3((MC * 64) / 256), blk, 0, stream>>>(x, x_emb, pos_emb, cpr, h, b0);

    for (int l = 0; l < L_; ++l) {
      // qkv = h @ Wqkv^T + bqkv   [MC,768] bf16, K=256  -> R
      gemm_bf16_kernel<0, false, false><<<dim3((MC / 128) * (768 / 128)), blk, 0, stream>>>(
          h, bWqkv + (size_t)l * 768 * 256, bqkv + (size_t)l * 768, nullptr, R, MC, 768, 256);
      // o = attention(qkv)   [MC,256] bf16  -> X
      attn_kernel<<<dim3(BC * 2), blk, 0, stream>>>(R, X);
      // h = LN1( X @ Wo^T + bo + h )   fused, in-place on h, K=256
      gemm_ln_kernel<<<dim3(MC / 64), blk, 0, stream>>>(
          X, bWo + (size_t)l * 256 * 256, bo + (size_t)l * 256, h,
          ln1_g + (size_t)l * 256, ln1_b + (size_t)l * 256, h, MC, 256);
      // f = gelu(h @ W1^T + b1)   [MC,1024] bf16, K=256  -> R
      gemm_bf16_kernel<1, false, false><<<dim3((MC / 128) * (FF_ / 128)), blk, 0, stream>>>(
          h, bW1 + (size_t)l * 1024 * 256, b1 + (size_t)l * 1024, nullptr, R, MC, 1024, 256);
      // h = LN2( R @ W2^T + b2 + h )   fused, in-place on h, K=1024
      gemm_ln_kernel<<<dim3(MC / 64), blk, 0, stream>>>(
          R, bW2 + (size_t)l * 256 * 1024, b2 + (size_t)l * 256, h,
          ln2_g + (size_t)l * 256, ln2_b + (size_t)l * 256, h, MC, 1024);
    }

    // Head MLP (chunk-local)
    gemm_bf16_kernel<2, false, false><<<dim3((MC / 128) * (U_ / 128)), blk, 0, stream>>>(
        h, bmW0, mb0, nullptr, R, MC, U_, E_);           // z0 = relu(.) -> R
    gemm_bf16_kernel<2, false, false><<<dim3((MC / 128) * (U_ / 128)), blk, 0, stream>>>(
        R, bmW1, mb1, nullptr, X, MC, U_, U_);           // z1 = relu(.) -> X
    // fused logits + logprob: out[b] directly, no logits materialization
    gemm_lp_kernel<<<dim3(MC / 64), blk, 0, stream>>>(X, bmW2, mb2, x, out, b0);
  }
}